// Round 14
// baseline (111.074 us; speedup 1.0000x reference)
//
#include <hip/hip_runtime.h>
#include <hip/hip_fp8.h>

#define BB 8
#define NN 4096
#define MM 4096
#define DD 128

typedef float f32x4  __attribute__((ext_vector_type(4)));
typedef float f32x16 __attribute__((ext_vector_type(16)));
typedef int   i32x4  __attribute__((ext_vector_type(4)));
typedef int   i32x8  __attribute__((ext_vector_type(8)));

// ---------------------------------------------------------------------------
// R33 (2nd submit — R33 bench never ran: GPUAcquisitionTimeout).
// R31 + asm-held x prefetch at (512,3). R31 measured: total 107.4
// (main ~37 via the stable total = main + 70.3 relation), best yet.
// Updated model: time ~= floor(~30us) + traffic/34TB/s. The ~30us floor =
// ~560 cyc/tile-batch at 4 w/SIMD — consistent with DEPTH-0 x-load latency
// (~300 cyc L2) sitting on the critical path: R31 dropped the prefetch to
// fit (512,4)'s 128-VGPR cap. R28's prefetch-null was on the 256-thread
// structure; not transferable. This round: __launch_bounds__(512,3) lifts
// the cap to 170 VGPR; restore ISSUE_X/WAIT_X ring-of-2 (state ~131 < 170).
// Occupancy cost 16->12 w/CU (cheap: R25->R26's 8->16 step was ~1.5us).
// vmcnt exact: only in-loop vmem is the 4 x loads/iter; batch-0 issued
// before the barrier (drained there); WAIT vmcnt(4) mid-loop, (0) last.
// Tripwires: WRITE_SIZE (spill -> ~118MB, R24) / first-dispatch anomaly.
// If main stays >=35us: all structural axes exhausted -> declare plateau.
//
// Fixed harness cost: ~44us 256MiB fillBufferAligned re-poison in-window;
// fixed total-vs-main offset ~70.3us (fills+prep+finalize+gaps).
//
// R19-31 retained: fragment-ordered fp8 (absmax 0 throughout), HALF-norms +
// negated y (acc=sq/2), mfma_scale_f32_32x32x64_f8f6f4 identity scale 127,
// balanced per-XCD patch (3MB < 4MB XCD L2), coalesced LDS-staged prep,
// all-y-staged prologue (64KB shared by 8 waves), barrier-free batch loop.
// LESSONS: merged finalize regresses (R11/12/15/16); cooperative launch
// fails (R14); prep transport not the gap (R21); per-batch barriers ~2x at
// low occ (R23); spills catastrophic (R24); TLP alone null (R26); compiler
// sinks plain-HIP prefetch (R27); 256-thr-shape prefetch null (R28);
// per-work halving null (R29); traffic halving = +5us only (R31).
// ---------------------------------------------------------------------------

typedef const __attribute__((address_space(1))) unsigned int* gas_ptr;
typedef __attribute__((address_space(3))) unsigned int* las_ptr;
static __device__ __forceinline__ void gload_lds16(const unsigned char* g,
                                                   unsigned char* l) {
    __builtin_amdgcn_global_load_lds((gas_ptr)g, (las_ptr)l, 16, 0, 0);
}

// Issue the 4 x-fragment loads for one batch into held registers.
// Volatile asm: cannot be sunk or deleted (R27 lesson).
#define ISSUE_X(dst, addr)                                                  \
    asm volatile("global_load_dwordx4 %0, %4, off\n\t"                      \
                 "global_load_dwordx4 %1, %4, off offset:16\n\t"            \
                 "global_load_dwordx4 %2, %4, off offset:2048\n\t"          \
                 "global_load_dwordx4 %3, %4, off offset:2064"              \
                 : "=&v"(dst[0]), "=&v"(dst[1]), "=&v"(dst[2]), "=&v"(dst[3]) \
                 : "v"(addr))

// Gate consumption: wait until <=N vmem outstanding, tying the values so
// consumers can't be hoisted (rule 18: + sched_barrier).
#define WAIT_X(buf, N)                                                      \
    do {                                                                    \
        asm volatile("s_waitcnt vmcnt(" #N ")"                              \
                     : "+v"(buf[0]), "+v"(buf[1]), "+v"(buf[2]), "+v"(buf[3])); \
        __builtin_amdgcn_sched_barrier(0);                                  \
    } while (0)

// Prep v2 (R21, unchanged): 2048 blocks x 256 threads, one 32-row fragment
// group (4KB) per block; coalesced reads -> cvt -> LDS permute -> coalesced
// 16B stores. Also inits fwd/bsum/fsum/counter and writes half-norms.
__global__ __launch_bounds__(256)
void prep_all(const float* __restrict__ x, const float* __restrict__ y,
              unsigned char* __restrict__ xq, unsigned char* __restrict__ yq,
              float* __restrict__ x2, float* __restrict__ y2,
              unsigned int* __restrict__ fwd, float* __restrict__ bsum,
              float* __restrict__ fsum, unsigned int* __restrict__ counter) {
    __shared__ i32x4 lbuf[256];  // 4 KB fragment-ordered staging

    const int tid  = threadIdx.x;
    const int g    = blockIdx.x;
    const int gtid = g * 256 + tid;
    if (gtid < BB * MM) fwd[gtid] = 0x7f800000u;  // +inf bits
    if (gtid == 0) { *bsum = 0.0f; *fsum = 0.0f; *counter = 0u; }

    const int rl = tid >> 3;   // row within group (0..31)
    const int c  = tid & 7;    // 16-float chunk within row (0..7)

    const float* src;
    unsigned char* dst;
    float* sq;
    float sgn;
    int row;
    if (g < 1024) {
        src = x; dst = xq + (size_t)g * 4096; sq = x2; sgn = 1.0f;
        row = g * 32 + rl;
    } else {
        src = y; dst = yq + (size_t)(g - 1024) * 4096; sq = y2; sgn = -1.0f;
        row = (g - 1024) * 32 + rl;
    }

    const f32x4* base = (const f32x4*)(src + (size_t)row * DD + c * 16);
    f32x4 v[4];
    #pragma unroll
    for (int j = 0; j < 4; ++j) v[j] = base[j];

    float s = 0.0f;
    #pragma unroll
    for (int j = 0; j < 4; ++j)
        s += v[j].x * v[j].x + v[j].y * v[j].y + v[j].z * v[j].z + v[j].w * v[j].w;

    i32x4 d;
    #pragma unroll
    for (int j = 0; j < 4; ++j) {
        unsigned int dj = (unsigned int)__builtin_amdgcn_cvt_pk_fp8_f32(
            sgn * v[j].x, sgn * v[j].y, 0, false);
        dj = (unsigned int)__builtin_amdgcn_cvt_pk_fp8_f32(
            sgn * v[j].z, sgn * v[j].w, (int)dj, true);
        d[j] = (int)dj;
    }

    const int lds_off = (c >> 2) * 2048 + ((c >> 1) & 1) * 1024
                      + rl * 32 + (c & 1) * 16;
    *(i32x4*)((char*)lbuf + lds_off) = d;

    #pragma unroll
    for (int m = 4; m; m >>= 1) s += __shfl_xor(s, m, 64);
    if (c == 0) sq[row] = 0.5f * s;

    __syncthreads();
    *(i32x4*)(dst + (size_t)tid * 16) = lbuf[tid];
}

// ---------------------------------------------------------------------------
// Main v11: 1024 blocks (256n x 64m), 8 waves of 32n x 64m, all-y-staged
// prologue, barrier-free loop, asm-held ring-of-2 x prefetch at (512,3).
// ---------------------------------------------------------------------------
__global__ __launch_bounds__(512, 3)
void chamfer_main(const unsigned char* __restrict__ xq, const unsigned char* __restrict__ yq,
                  const float* __restrict__ x2, const float* __restrict__ y2,
                  unsigned int* __restrict__ fwd, float* __restrict__ bpart) {
    __shared__ float x2s[BB][256];            // 8 KB
    __shared__ float y2s[BB][64];             // 2 KB
    __shared__ unsigned int fbuf[BB][64];     // 2 KB
    __shared__ unsigned char ybuf[BB][8192];  // 64 KB: ALL batches of y-frags
    __shared__ float red[8];

    const int tid   = threadIdx.x;
    const int lane  = tid & 63;
    const int wave  = tid >> 6;    // 0..7
    const int lhalf = lane >> 5;
    const int l31   = lane & 31;

    const int id  = blockIdx.x;
    const int xcd = id & 7;
    const int j   = id >> 3;                   // 0..127
    const int nb  = (xcd >> 1) * 4 + (j & 3);  // 0..15  (256 n each)
    const int mb  = (xcd & 1) * 32 + (j >> 2); // 0..63  (64 m each)
    const int n0b = nb * 256;
    const int n0w = n0b + wave * 32;
    const int m0  = mb * 64;

    // x fragment base (per-wave, asm-held ring-of-2)
    const size_t laneoff = (size_t)lhalf * 1024 + (size_t)l31 * 32;
    const unsigned char* xbase = xq + (size_t)(n0w >> 5) * 4096 + laneoff;

    // y staging, source-swizzled so LDS is dense (R24/R31-verified formula):
    // wave = chunk c -> (t,i,lh) = (c>>2,(c>>1)&1,c&1); lane -> l31*32+hh*16
    const size_t ysw = (size_t)(wave >> 2) * 4096 + (size_t)((wave >> 1) & 1) * 2048
                     + (size_t)(wave & 1) * 1024 + (size_t)l31 * 32
                     + (size_t)lhalf * 16;
    const unsigned char* ybase = yq + (size_t)mb * 8192 + ysw;

    // prologue: stage ALL 8 batches of y (1 gload_lds per wave per batch)
    #pragma unroll
    for (int b = 0; b < BB; ++b)
        gload_lds16(ybase + ((size_t)b << 19), &ybuf[b][wave * 1024]);

    // x ring-of-2, asm-held: fxr[buf][0..3] = {i0h0, i0h1, i1h0, i1h1}
    i32x4 fxr[2][4];
    ISSUE_X(fxr[0], xbase);   // batch 0 — drained by the prologue barrier

    for (int i = tid; i < BB * 256; i += 512)
        x2s[i >> 8][i & 255] = x2[(size_t)(i >> 8) * NN + n0b + (i & 255)];
    {
        int i = tid;  // exactly BB*64 = 512 items
        y2s[i >> 6][i & 63] = y2[(size_t)(i >> 6) * MM + m0 + (i & 63)];
        ((unsigned int*)fbuf)[i] = 0x7f800000u;
    }
    __syncthreads();  // drains ALL staging (vmcnt 0): y LDS + batch-0 x regs

    const float INF = __builtin_inff();
    float bmin[2][16];  // [m-tile][reg] running min of acc = sq/2
    #pragma unroll
    for (int t = 0; t < 2; ++t)
        #pragma unroll
        for (int r = 0; r < 16; ++r) bmin[t][r] = INF;

    const int rb0 = lhalf * 1024 + l31 * 16;  // dense y read base

    #pragma unroll   // FULL unroll: ring indices compile-time
    for (int b = 0; b < BB; ++b) {
        const int cur = b & 1;
        // issue next batch's x FIRST (volatile: stays here, stays issued)
        if (b < BB - 1)
            ISSUE_X(fxr[cur ^ 1], (xbase + ((size_t)(b + 1) << 19)));

        // gate batch b's x; next-batch 4 loads stay in flight across the
        // whole compute phase below.
        if (b < BB - 1) { WAIT_X(fxr[cur], 4); }
        else            { WAIT_X(fxr[cur], 0); }

        // acc seeds: (x2+y2)/2 -> MFMA (neg-y fp8) yields acc = sq/2
        // C/D: col = l31, row = (r&3) + 8*(r>>2) + 4*lhalf
        float y2v[2];
        y2v[0] = y2s[b][l31];
        y2v[1] = y2s[b][32 + l31];
        f32x16 acc[2];
        #pragma unroll
        for (int q = 0; q < 4; ++q) {
            f32x4 xv = *(const f32x4*)&x2s[b][wave * 32 + lhalf * 4 + q * 8];
            #pragma unroll
            for (int t = 0; t < 2; ++t)
                #pragma unroll
                for (int e = 0; e < 4; ++e)
                    acc[t][q * 4 + e] = xv[e] + y2v[t];
        }

        #pragma unroll
        for (int i = 0; i < 2; ++i) {
            i32x8 av = __builtin_shufflevector(fxr[cur][2 * i], fxr[cur][2 * i + 1],
                                               0, 1, 2, 3, 4, 5, 6, 7);
            #pragma unroll
            for (int t = 0; t < 2; ++t) {
                const unsigned char* yb = &ybuf[b][t * 4096 + i * 2048 + rb0];
                i32x4 lo = *(const i32x4*)(yb);
                i32x4 hi = *(const i32x4*)(yb + 512);
                i32x8 bv = __builtin_shufflevector(lo, hi, 0, 1, 2, 3, 4, 5, 6, 7);
                acc[t] = __builtin_amdgcn_mfma_scale_f32_32x32x64_f8f6f4(
                    av, bv, acc[t], 0, 0, 0, 127, 0, 127);
            }
        }

        // epilogue: pure fmin (acc IS sq/2)
        float fm[2] = {INF, INF};
        #pragma unroll
        for (int t = 0; t < 2; ++t)
            #pragma unroll
            for (int r = 0; r < 16; ++r) {
                bmin[t][r] = fminf(bmin[t][r], acc[t][r]);
                fm[t]      = fminf(fm[t], acc[t][r]);
            }
        #pragma unroll
        for (int t = 0; t < 2; ++t)
            atomicMin(&fbuf[b][t * 32 + l31],
                      __float_as_uint(fmaxf(fm[t], 0.0f)));
    }
    __syncthreads();  // fbuf atomics from all waves complete

    // flush forward mins (values are sq/2; finalize applies the 2x)
    {
        int i = tid;  // exactly BB*64 = 512 items
        atomicMin(&fwd[(size_t)(i >> 6) * MM + m0 + (i & 63)], fbuf[i >> 6][i & 63]);
    }

    // backward: sqrt(2 * clamp(min sq/2)), block-reduce, one store/block
    float s = 0.0f;
    #pragma unroll
    for (int t = 0; t < 2; ++t)
        #pragma unroll
        for (int r = 0; r < 16; ++r)
            s += sqrtf(2.0f * fmaxf(bmin[t][r], 0.0f));
    #pragma unroll
    for (int off = 32; off; off >>= 1) s += __shfl_down(s, off, 64);
    if (lane == 0) red[wave] = s;
    __syncthreads();
    if (tid == 0)
        bpart[id] = red[0] + red[1] + red[2] + red[3]
                  + red[4] + red[5] + red[6] + red[7];
}

// Finalize: 32 blocks x 256 threads. fwd holds min sq/2 -> dist = sqrt(2v).
__global__ __launch_bounds__(256)
void finalize_kernel(const unsigned int* __restrict__ fwd,
                     const float* __restrict__ bpart,
                     float* __restrict__ bsum, float* __restrict__ fsum,
                     unsigned int* __restrict__ counter, float* __restrict__ out) {
    __shared__ float redf[4], redb[4];
    __shared__ int isLast;
    const int tid = threadIdx.x, lane = tid & 63, wave = tid >> 6;
    const int gtid = blockIdx.x * 256 + tid;
    uint4 u = ((const uint4*)fwd)[gtid];
    float sf = sqrtf(2.0f * __uint_as_float(u.x)) + sqrtf(2.0f * __uint_as_float(u.y)) +
               sqrtf(2.0f * __uint_as_float(u.z)) + sqrtf(2.0f * __uint_as_float(u.w));
    float sb = (gtid < 1024) ? bpart[gtid] : 0.0f;   // 1024 main blocks
    #pragma unroll
    for (int off = 32; off; off >>= 1) {
        sf += __shfl_down(sf, off, 64);
        sb += __shfl_down(sb, off, 64);
    }
    if (lane == 0) { redf[wave] = sf; redb[wave] = sb; }
    __syncthreads();
    if (tid == 0) {
        atomicAdd(fsum, redf[0] + redf[1] + redf[2] + redf[3]);
        atomicAdd(bsum, redb[0] + redb[1] + redb[2] + redb[3]);
        __threadfence();
        unsigned int c = atomicAdd(counter, 1u);
        isLast = (c == gridDim.x - 1) ? 1 : 0;
        if (isLast) {
            __threadfence();
            float fs = __hip_atomic_load(fsum, __ATOMIC_RELAXED,
                                         __HIP_MEMORY_SCOPE_AGENT);
            float bs = __hip_atomic_load(bsum, __ATOMIC_RELAXED,
                                         __HIP_MEMORY_SCOPE_AGENT);
            out[0] = fs / (float)(BB * MM) + bs / ((float)NN * (float)MM);
        }
    }
}

extern "C" void kernel_launch(void* const* d_in, const int* in_sizes, int n_in,
                              void* d_out, int out_size, void* d_ws, size_t ws_size,
                              hipStream_t stream) {
    const float* x = (const float*)d_in[0];  // (B,N,D)
    const float* y = (const float*)d_in[1];  // (B,M,D)
    float* out = (float*)d_out;

    char* w = (char*)d_ws;
    unsigned char* xq = (unsigned char*)(w);               // 4 MB fp8 (frag order)
    unsigned char* yq = (unsigned char*)(w + 4194304);     // 4 MB fp8, NEGATED
    float*    x2 = (float*)(w + 8388608);                  // 128 KB (x2/2)
    float*    y2 = (float*)(w + 8519680);                  // 128 KB (y2/2)
    unsigned int* fwd = (unsigned int*)(w + 8650752);      // 128 KB (min sq/2)
    float*    bpart = (float*)(w + 8781824);               // 4 KB (1024 blocks)
    float*    bsum = (float*)(w + 8798208);                // 4 B
    float*    fsum = (float*)(w + 8798212);                // 4 B
    unsigned int* counter = (unsigned int*)(w + 8798216);  // 4 B

    prep_all<<<2048, 256, 0, stream>>>(x, y, xq, yq, x2, y2,
                                       fwd, bsum, fsum, counter);
    chamfer_main<<<1024, 512, 0, stream>>>(xq, yq, x2, y2, fwd, bpart);
    finalize_kernel<<<32, 256, 0, stream>>>(fwd, bpart, bsum, fsum, counter, out);
}

// Round 15
// 107.640 us; speedup vs baseline: 1.0319x; 1.0319x over previous
//
#include <hip/hip_runtime.h>
#include <hip/hip_fp8.h>

#define BB 8
#define NN 4096
#define MM 4096
#define DD 128

typedef float f32x4  __attribute__((ext_vector_type(4)));
typedef float f32x16 __attribute__((ext_vector_type(16)));
typedef int   i32x4  __attribute__((ext_vector_type(4)));
typedef int   i32x8  __attribute__((ext_vector_type(8)));

// ---------------------------------------------------------------------------
// R35 = REVERT to R31 (best measured: 107.4us total, main ~37us, absmax 0).
// R33 (asm-held prefetch at (512,3), 12 w/CU) measured 111.1 — regression:
// wave-density loss > prefetch gain. That falsifies the last open theory
// (depth-0 x-load latency). All structural axes now measured:
//   traffic cut 2.7x (R22: real), barrier-free loop (R25: real), TLP 2x
//   (R26: ~null), prefetch depth 1-3 incl. asm-forced (R27/28/33:
//   null/null/negative), per-tile overhead halved (R29: null), traffic+TLP
//   combined (R31: best).
// Residual main ~37us = latency plateau (~560 cyc/tile; Mfma 14 / VALU 40 /
// HBM 5 / conflicts 0 — no pipe near ceiling). Past this requires a
// producer-consumer schedule that R23 (barrier cost at low occ) and R24
// (128-VGPR spill cliff at 8 waves) jointly box out at this geometry.
// Controllable window: main 37 + prep ~15 + finalize ~2 of the 107 total;
// rest is harness 256MiB re-poison fills (~44us each) and launch gaps.
//
// Geometry: 8-wave 512-thread blocks, 256n x 64m, ALL y staged in prologue
// (64KB shared by 8 waves -> 2 blocks/CU = 16 w/CU), barrier-free batch
// loop, point-of-use x loads (state ~115 VGPR < 128 cap of (512,4)).
// R19-31 retained: fragment-ordered fp8, HALF-norms + negated y (acc=sq/2),
// mfma_scale_f32_32x32x64_f8f6f4 identity scale 127, balanced per-XCD patch
// (3MB < 4MB XCD L2), coalesced LDS-staged prep.
// ---------------------------------------------------------------------------

typedef const __attribute__((address_space(1))) unsigned int* gas_ptr;
typedef __attribute__((address_space(3))) unsigned int* las_ptr;
static __device__ __forceinline__ void gload_lds16(const unsigned char* g,
                                                   unsigned char* l) {
    __builtin_amdgcn_global_load_lds((gas_ptr)g, (las_ptr)l, 16, 0, 0);
}

// Prep v2 (R21, unchanged): 2048 blocks x 256 threads, one 32-row fragment
// group (4KB) per block; coalesced reads -> cvt -> LDS permute -> coalesced
// 16B stores. Also inits fwd/bsum/fsum/counter and writes half-norms.
__global__ __launch_bounds__(256)
void prep_all(const float* __restrict__ x, const float* __restrict__ y,
              unsigned char* __restrict__ xq, unsigned char* __restrict__ yq,
              float* __restrict__ x2, float* __restrict__ y2,
              unsigned int* __restrict__ fwd, float* __restrict__ bsum,
              float* __restrict__ fsum, unsigned int* __restrict__ counter) {
    __shared__ i32x4 lbuf[256];  // 4 KB fragment-ordered staging

    const int tid  = threadIdx.x;
    const int g    = blockIdx.x;
    const int gtid = g * 256 + tid;
    if (gtid < BB * MM) fwd[gtid] = 0x7f800000u;  // +inf bits
    if (gtid == 0) { *bsum = 0.0f; *fsum = 0.0f; *counter = 0u; }

    const int rl = tid >> 3;   // row within group (0..31)
    const int c  = tid & 7;    // 16-float chunk within row (0..7)

    const float* src;
    unsigned char* dst;
    float* sq;
    float sgn;
    int row;
    if (g < 1024) {
        src = x; dst = xq + (size_t)g * 4096; sq = x2; sgn = 1.0f;
        row = g * 32 + rl;
    } else {
        src = y; dst = yq + (size_t)(g - 1024) * 4096; sq = y2; sgn = -1.0f;
        row = (g - 1024) * 32 + rl;
    }

    const f32x4* base = (const f32x4*)(src + (size_t)row * DD + c * 16);
    f32x4 v[4];
    #pragma unroll
    for (int j = 0; j < 4; ++j) v[j] = base[j];

    float s = 0.0f;
    #pragma unroll
    for (int j = 0; j < 4; ++j)
        s += v[j].x * v[j].x + v[j].y * v[j].y + v[j].z * v[j].z + v[j].w * v[j].w;

    i32x4 d;
    #pragma unroll
    for (int j = 0; j < 4; ++j) {
        unsigned int dj = (unsigned int)__builtin_amdgcn_cvt_pk_fp8_f32(
            sgn * v[j].x, sgn * v[j].y, 0, false);
        dj = (unsigned int)__builtin_amdgcn_cvt_pk_fp8_f32(
            sgn * v[j].z, sgn * v[j].w, (int)dj, true);
        d[j] = (int)dj;
    }

    const int lds_off = (c >> 2) * 2048 + ((c >> 1) & 1) * 1024
                      + rl * 32 + (c & 1) * 16;
    *(i32x4*)((char*)lbuf + lds_off) = d;

    #pragma unroll
    for (int m = 4; m; m >>= 1) s += __shfl_xor(s, m, 64);
    if (c == 0) sq[row] = 0.5f * s;

    __syncthreads();
    *(i32x4*)(dst + (size_t)tid * 16) = lbuf[tid];
}

// ---------------------------------------------------------------------------
// Main v10 (R31): 1024 blocks (256n x 64m), 8 waves of 32n x 64m,
// all-y-staged prologue (64KB shared -> 16 w/CU), barrier-free loop,
// point-of-use x loads (no ring -> no spill).
// ---------------------------------------------------------------------------
__global__ __launch_bounds__(512, 4)
void chamfer_main(const unsigned char* __restrict__ xq, const unsigned char* __restrict__ yq,
                  const float* __restrict__ x2, const float* __restrict__ y2,
                  unsigned int* __restrict__ fwd, float* __restrict__ bpart) {
    __shared__ float x2s[BB][256];            // 8 KB
    __shared__ float y2s[BB][64];             // 2 KB
    __shared__ unsigned int fbuf[BB][64];     // 2 KB
    __shared__ unsigned char ybuf[BB][8192];  // 64 KB: ALL batches of y-frags
    __shared__ float red[8];

    const int tid   = threadIdx.x;
    const int lane  = tid & 63;
    const int wave  = tid >> 6;    // 0..7
    const int lhalf = lane >> 5;
    const int l31   = lane & 31;

    const int id  = blockIdx.x;
    const int xcd = id & 7;
    const int j   = id >> 3;                   // 0..127
    const int nb  = (xcd >> 1) * 4 + (j & 3);  // 0..15  (256 n each)
    const int mb  = (xcd & 1) * 32 + (j >> 2); // 0..63  (64 m each)
    const int n0b = nb * 256;
    const int n0w = n0b + wave * 32;
    const int m0  = mb * 64;

    // x fragment base (per-wave, point-of-use loads)
    const size_t laneoff = (size_t)lhalf * 1024 + (size_t)l31 * 32;
    const unsigned char* xbase = xq + (size_t)(n0w >> 5) * 4096 + laneoff;

    // y staging, source-swizzled so LDS is dense (R24/R31-verified formula):
    // wave = chunk c -> (t,i,lh) = (c>>2,(c>>1)&1,c&1); lane -> l31*32+hh*16
    const size_t ysw = (size_t)(wave >> 2) * 4096 + (size_t)((wave >> 1) & 1) * 2048
                     + (size_t)(wave & 1) * 1024 + (size_t)l31 * 32
                     + (size_t)lhalf * 16;
    const unsigned char* ybase = yq + (size_t)mb * 8192 + ysw;

    // prologue: stage ALL 8 batches of y (1 gload_lds per wave per batch)
    #pragma unroll
    for (int b = 0; b < BB; ++b)
        gload_lds16(ybase + ((size_t)b << 19), &ybuf[b][wave * 1024]);

    for (int i = tid; i < BB * 256; i += 512)
        x2s[i >> 8][i & 255] = x2[(size_t)(i >> 8) * NN + n0b + (i & 255)];
    {
        int i = tid;  // exactly BB*64 = 512 items
        y2s[i >> 6][i & 63] = y2[(size_t)(i >> 6) * MM + m0 + (i & 63)];
        ((unsigned int*)fbuf)[i] = 0x7f800000u;
    }
    __syncthreads();  // the ONLY barrier before the loop (drains staging)

    const float INF = __builtin_inff();
    float bmin[2][16];  // [m-tile][reg] running min of acc = sq/2
    #pragma unroll
    for (int t = 0; t < 2; ++t)
        #pragma unroll
        for (int r = 0; r < 16; ++r) bmin[t][r] = INF;

    const int rb0 = lhalf * 1024 + l31 * 16;  // dense y read base

    #pragma unroll 2
    for (int b = 0; b < BB; ++b) {
        // x for batch b: point-of-use (NO ring — R24's +32 VGPR dbuf spilled;
        // R33 measured the (512,3)+ring alternative at -3.7us vs this)
        const unsigned char* xb = xbase + ((size_t)b << 19);
        i32x4 fx[2][2];
        #pragma unroll
        for (int i = 0; i < 2; ++i)
            #pragma unroll
            for (int hh = 0; hh < 2; ++hh)
                fx[i][hh] = *(const i32x4*)(xb + i * 2048 + hh * 16);

        // acc seeds: (x2+y2)/2 -> MFMA (neg-y fp8) yields acc = sq/2
        // C/D: col = l31, row = (r&3) + 8*(r>>2) + 4*lhalf
        float y2v[2];
        y2v[0] = y2s[b][l31];
        y2v[1] = y2s[b][32 + l31];
        f32x16 acc[2];
        #pragma unroll
        for (int q = 0; q < 4; ++q) {
            f32x4 xv = *(const f32x4*)&x2s[b][wave * 32 + lhalf * 4 + q * 8];
            #pragma unroll
            for (int t = 0; t < 2; ++t)
                #pragma unroll
                for (int e = 0; e < 4; ++e)
                    acc[t][q * 4 + e] = xv[e] + y2v[t];
        }

        #pragma unroll
        for (int i = 0; i < 2; ++i) {
            i32x8 av = __builtin_shufflevector(fx[i][0], fx[i][1],
                                               0, 1, 2, 3, 4, 5, 6, 7);
            #pragma unroll
            for (int t = 0; t < 2; ++t) {
                const unsigned char* yb = &ybuf[b][t * 4096 + i * 2048 + rb0];
                i32x4 lo = *(const i32x4*)(yb);
                i32x4 hi = *(const i32x4*)(yb + 512);
                i32x8 bv = __builtin_shufflevector(lo, hi, 0, 1, 2, 3, 4, 5, 6, 7);
                acc[t] = __builtin_amdgcn_mfma_scale_f32_32x32x64_f8f6f4(
                    av, bv, acc[t], 0, 0, 0, 127, 0, 127);
            }
        }

        // epilogue: pure fmin (acc IS sq/2)
        float fm[2] = {INF, INF};
        #pragma unroll
        for (int t = 0; t < 2; ++t)
            #pragma unroll
            for (int r = 0; r < 16; ++r) {
                bmin[t][r] = fminf(bmin[t][r], acc[t][r]);
                fm[t]      = fminf(fm[t], acc[t][r]);
            }
        #pragma unroll
        for (int t = 0; t < 2; ++t)
            atomicMin(&fbuf[b][t * 32 + l31],
                      __float_as_uint(fmaxf(fm[t], 0.0f)));
    }
    __syncthreads();  // fbuf atomics from all waves complete

    // flush forward mins (values are sq/2; finalize applies the 2x)
    {
        int i = tid;  // exactly BB*64 = 512 items
        atomicMin(&fwd[(size_t)(i >> 6) * MM + m0 + (i & 63)], fbuf[i >> 6][i & 63]);
    }

    // backward: sqrt(2 * clamp(min sq/2)), block-reduce, one store/block
    float s = 0.0f;
    #pragma unroll
    for (int t = 0; t < 2; ++t)
        #pragma unroll
        for (int r = 0; r < 16; ++r)
            s += sqrtf(2.0f * fmaxf(bmin[t][r], 0.0f));
    #pragma unroll
    for (int off = 32; off; off >>= 1) s += __shfl_down(s, off, 64);
    if (lane == 0) red[wave] = s;
    __syncthreads();
    if (tid == 0)
        bpart[id] = red[0] + red[1] + red[2] + red[3]
                  + red[4] + red[5] + red[6] + red[7];
}

// Finalize: 32 blocks x 256 threads. fwd holds min sq/2 -> dist = sqrt(2v).
__global__ __launch_bounds__(256)
void finalize_kernel(const unsigned int* __restrict__ fwd,
                     const float* __restrict__ bpart,
                     float* __restrict__ bsum, float* __restrict__ fsum,
                     unsigned int* __restrict__ counter, float* __restrict__ out) {
    __shared__ float redf[4], redb[4];
    __shared__ int isLast;
    const int tid = threadIdx.x, lane = tid & 63, wave = tid >> 6;
    const int gtid = blockIdx.x * 256 + tid;
    uint4 u = ((const uint4*)fwd)[gtid];
    float sf = sqrtf(2.0f * __uint_as_float(u.x)) + sqrtf(2.0f * __uint_as_float(u.y)) +
               sqrtf(2.0f * __uint_as_float(u.z)) + sqrtf(2.0f * __uint_as_float(u.w));
    float sb = (gtid < 1024) ? bpart[gtid] : 0.0f;   // 1024 main blocks
    #pragma unroll
    for (int off = 32; off; off >>= 1) {
        sf += __shfl_down(sf, off, 64);
        sb += __shfl_down(sb, off, 64);
    }
    if (lane == 0) { redf[wave] = sf; redb[wave] = sb; }
    __syncthreads();
    if (tid == 0) {
        atomicAdd(fsum, redf[0] + redf[1] + redf[2] + redf[3]);
        atomicAdd(bsum, redb[0] + redb[1] + redb[2] + redb[3]);
        __threadfence();
        unsigned int c = atomicAdd(counter, 1u);
        isLast = (c == gridDim.x - 1) ? 1 : 0;
        if (isLast) {
            __threadfence();
            float fs = __hip_atomic_load(fsum, __ATOMIC_RELAXED,
                                         __HIP_MEMORY_SCOPE_AGENT);
            float bs = __hip_atomic_load(bsum, __ATOMIC_RELAXED,
                                         __HIP_MEMORY_SCOPE_AGENT);
            out[0] = fs / (float)(BB * MM) + bs / ((float)NN * (float)MM);
        }
    }
}

extern "C" void kernel_launch(void* const* d_in, const int* in_sizes, int n_in,
                              void* d_out, int out_size, void* d_ws, size_t ws_size,
                              hipStream_t stream) {
    const float* x = (const float*)d_in[0];  // (B,N,D)
    const float* y = (const float*)d_in[1];  // (B,M,D)
    float* out = (float*)d_out;

    char* w = (char*)d_ws;
    unsigned char* xq = (unsigned char*)(w);               // 4 MB fp8 (frag order)
    unsigned char* yq = (unsigned char*)(w + 4194304);     // 4 MB fp8, NEGATED
    float*    x2 = (float*)(w + 8388608);                  // 128 KB (x2/2)
    float*    y2 = (float*)(w + 8519680);                  // 128 KB (y2/2)
    unsigned int* fwd = (unsigned int*)(w + 8650752);      // 128 KB (min sq/2)
    float*    bpart = (float*)(w + 8781824);               // 4 KB (1024 blocks)
    float*    bsum = (float*)(w + 8798208);                // 4 B
    float*    fsum = (float*)(w + 8798212);                // 4 B
    unsigned int* counter = (unsigned int*)(w + 8798216);  // 4 B

    prep_all<<<2048, 256, 0, stream>>>(x, y, xq, yq, x2, y2,
                                       fwd, bsum, fsum, counter);
    chamfer_main<<<1024, 512, 0, stream>>>(xq, yq, x2, y2, fwd, bpart);
    finalize_kernel<<<32, 256, 0, stream>>>(fwd, bpart, bsum, fsum, counter, out);
}